// Round 1
// baseline (432.548 us; speedup 1.0000x reference)
//
#include <hip/hip_runtime.h>

#define D_NODE 128
#define D_EDGE 64
#define D_IN 192
#define D_OUT 128

// ---------------- CSR build ----------------

__global__ void k_hist(const int* __restrict__ dst, int* __restrict__ cnt, int E) {
    int e = blockIdx.x * 256 + threadIdx.x;
    if (e < E) atomicAdd(&cnt[dst[e]], 1);
}

// Single-block exclusive scan of cnt[0..N) -> offsets[0..N], cursor copy.
__global__ void k_scan(const int* __restrict__ cnt, int* __restrict__ offsets,
                       int* __restrict__ cursor, int N) {
    __shared__ int buf[256];
    __shared__ int s_carry;
    int tid = threadIdx.x;
    if (tid == 0) s_carry = 0;
    __syncthreads();
    for (int base = 0; base < N; base += 256) {
        int i = base + tid;
        int v = (i < N) ? cnt[i] : 0;
        buf[tid] = v;
        __syncthreads();
        int val = v;
        for (int off = 1; off < 256; off <<= 1) {
            int t = (tid >= off) ? buf[tid - off] : 0;
            __syncthreads();
            val += t;
            buf[tid] = val;
            __syncthreads();
        }
        int carry = s_carry;
        int excl = val - v;
        if (i < N) { int o = carry + excl; offsets[i] = o; cursor[i] = o; }
        __syncthreads();                 // all reads of s_carry done
        if (tid == 255) s_carry = carry + val;  // val@255 == chunk total (inclusive)
        __syncthreads();
    }
    if (tid == 0) offsets[N] = s_carry;
}

__global__ void k_scatter(const int* __restrict__ ei, int* __restrict__ cursor,
                          int2* __restrict__ csr, int E) {
    int e = blockIdx.x * 256 + threadIdx.x;
    if (e < E) {
        int s = ei[e];
        int d = ei[E + e];
        int pos = atomicAdd(&cursor[d], 1);
        csr[pos] = make_int2(s, e);
    }
}

// ---------------- per-node gather + sum (wave per node) ----------------
// agg[n][0:128] = sum of x[src], agg[n][128:192] = sum of edge_features
__global__ __launch_bounds__(256) void k_gather(
        const float2* __restrict__ x2, const float* __restrict__ ef,
        const int* __restrict__ offsets, const int2* __restrict__ csr,
        float* __restrict__ agg, int N) {
    int wid = threadIdx.x >> 6;
    int lane = threadIdx.x & 63;
    int node = blockIdx.x * 4 + wid;
    if (node >= N) return;
    int start = offsets[node];
    int end = offsets[node + 1];
    float a0 = 0.0f, a1 = 0.0f, a2 = 0.0f;
    for (int base = start; base < end; base += 64) {
        int m = end - base;
        if (m > 64) m = 64;
        int2 ent = make_int2(0, 0);
        if (lane < m) ent = csr[base + lane];
        for (int j = 0; j < m; ++j) {
            int s  = __shfl(ent.x, j, 64);
            int id = __shfl(ent.y, j, 64);
            float2 xv = x2[(size_t)s * 64 + lane];   // elems 2*lane, 2*lane+1 of x row
            float  ev = ef[(size_t)id * 64 + lane];  // elem lane of ef row
            a0 += xv.x; a1 += xv.y; a2 += ev;
        }
    }
    float2* aggrow = (float2*)(agg + (size_t)node * D_IN);
    aggrow[lane] = make_float2(a0, a1);              // x part, elems 2*lane..2*lane+1
    agg[(size_t)node * D_IN + 128 + lane] = a2;      // ef part
}

// ---------------- small GEMM: out[n,o] = agg[n,:]@W[:,o]/cnt + b[o] ----------------
__global__ __launch_bounds__(256) void k_gemm(
        const float* __restrict__ agg, const float* __restrict__ W,
        const float* __restrict__ b, const int* __restrict__ offsets,
        float* __restrict__ out, int N) {
    __shared__ float sAgg[16][D_IN];
    __shared__ int scnt[16];
    int tid = threadIdx.x;
    int n0 = blockIdx.x * 16;
    for (int i = tid; i < 16 * D_IN; i += 256) {
        int m = i / D_IN;
        int k = i - m * D_IN;
        int n = n0 + m;
        sAgg[m][k] = (n < N) ? agg[(size_t)n * D_IN + k] : 0.0f;
    }
    if (tid < 16) {
        int n = n0 + tid;
        scnt[tid] = (n < N) ? (offsets[n + 1] - offsets[n]) : 0;
    }
    __syncthreads();
    int o = tid & 127;
    int g = tid >> 7;   // 0..1: which group of 8 nodes
    float acc[8];
#pragma unroll
    for (int m = 0; m < 8; ++m) acc[m] = 0.0f;
    for (int k = 0; k < D_IN; k += 4) {
        float w0 = W[(k + 0) * D_OUT + o];
        float w1 = W[(k + 1) * D_OUT + o];
        float w2 = W[(k + 2) * D_OUT + o];
        float w3 = W[(k + 3) * D_OUT + o];
#pragma unroll
        for (int m = 0; m < 8; ++m) {
            const float4 av = *(const float4*)(&sAgg[g * 8 + m][k]);
            acc[m] += av.x * w0 + av.y * w1 + av.z * w2 + av.w * w3;
        }
    }
    float bo = b[o];
#pragma unroll
    for (int m = 0; m < 8; ++m) {
        int n = n0 + g * 8 + m;
        if (n < N) {
            int c = scnt[g * 8 + m];
            out[(size_t)n * D_OUT + o] = (c > 0) ? (acc[m] / (float)c + bo) : 0.0f;
        }
    }
}

extern "C" void kernel_launch(void* const* d_in, const int* in_sizes, int n_in,
                              void* d_out, int out_size, void* d_ws, size_t ws_size,
                              hipStream_t stream) {
    const float* x  = (const float*)d_in[0];
    const int*   ei = (const int*)d_in[1];   // [2, E] flat: src at [0,E), dst at [E,2E)
    const float* ef = (const float*)d_in[2];
    const float* W  = (const float*)d_in[3];
    const float* b  = (const float*)d_in[4];
    float* out = (float*)d_out;

    const int N = in_sizes[0] / D_NODE;
    const int E = in_sizes[2] / D_EDGE;

    // workspace layout (64B aligned)
    auto align64 = [](size_t v) { return (v + 63) & ~(size_t)63; };
    char* ws = (char*)d_ws;
    size_t o_cnt = 0;
    size_t o_off = align64(o_cnt + (size_t)N * 4);
    size_t o_cur = align64(o_off + (size_t)(N + 1) * 4);
    size_t o_csr = align64(o_cur + (size_t)N * 4);
    size_t o_agg = align64(o_csr + (size_t)E * 8);
    int*  cnt     = (int*)(ws + o_cnt);
    int*  offsets = (int*)(ws + o_off);
    int*  cursor  = (int*)(ws + o_cur);
    int2* csr     = (int2*)(ws + o_csr);
    float* agg    = (float*)(ws + o_agg);

    hipMemsetAsync(cnt, 0, (size_t)N * 4, stream);
    k_hist<<<(E + 255) / 256, 256, 0, stream>>>(ei + E, cnt, E);
    k_scan<<<1, 256, 0, stream>>>(cnt, offsets, cursor, N);
    k_scatter<<<(E + 255) / 256, 256, 0, stream>>>(ei, cursor, csr, E);
    k_gather<<<(N + 3) / 4, 256, 0, stream>>>((const float2*)x, ef, offsets, csr, agg, N);
    k_gemm<<<(N + 15) / 16, 256, 0, stream>>>(agg, W, b, offsets, out, N);
}

// Round 2
// 376.086 us; speedup vs baseline: 1.1501x; 1.1501x over previous
//
#include <hip/hip_runtime.h>

#define D_NODE 128
#define D_EDGE 64
#define D_IN 192
#define D_OUT 128

// ---------------- CSR build ----------------

__global__ void k_hist(const int* __restrict__ dst, int* __restrict__ cnt, int E) {
    int e = blockIdx.x * 256 + threadIdx.x;
    if (e < E) atomicAdd(&cnt[dst[e]], 1);
}

// Single-block scan, thread-coarsened + wave-shuffle: 2 barriers total.
// Valid for N <= 16384 (CH <= 16). Problem has N = 10000.
__global__ __launch_bounds__(1024) void k_scan(const int* __restrict__ cnt,
                                               int* __restrict__ offsets,
                                               int* __restrict__ cursor, int N) {
    __shared__ int wsum[16];
    int tid = threadIdx.x;
    int lane = tid & 63, wid = tid >> 6;
    const int CH = (N + 1023) / 1024;          // 10 for N=10000
    int i0 = tid * CH;
    int local[16];
    int lsum = 0;
    for (int c = 0; c < CH; ++c) {
        int i = i0 + c;
        int v = (i < N) ? cnt[i] : 0;
        local[c] = v;
        lsum += v;
    }
    // inclusive wave scan of per-thread sums
    int incl = lsum;
    for (int off = 1; off < 64; off <<= 1) {
        int t = __shfl_up(incl, off, 64);
        if (lane >= off) incl += t;
    }
    if (lane == 63) wsum[wid] = incl;
    __syncthreads();
    if (wid == 0) {
        int s = (lane < 16) ? wsum[lane] : 0;
        for (int off = 1; off < 16; off <<= 1) {
            int t = __shfl_up(s, off, 64);
            if (lane >= off) s += t;
        }
        if (lane < 16) wsum[lane] = s;         // inclusive wave totals
    }
    __syncthreads();
    int waveoff = (wid > 0) ? wsum[wid - 1] : 0;
    int run = waveoff + incl - lsum;           // exclusive prefix for this thread
    for (int c = 0; c < CH; ++c) {
        int i = i0 + c;
        if (i < N) { offsets[i] = run; cursor[i] = run; run += local[c]; }
    }
    if (tid == 0) offsets[N] = wsum[15];
}

__global__ void k_scatter(const int* __restrict__ ei, int* __restrict__ cursor,
                          int2* __restrict__ csr, int E) {
    int e = blockIdx.x * 256 + threadIdx.x;
    if (e < E) {
        int s = ei[e];
        int d = ei[E + e];
        int pos = atomicAdd(&cursor[d], 1);
        csr[pos] = make_int2(s, e);
    }
}

// ---------------- per-node gather + sum (wave per node) ----------------
// agg[n][0:128] = sum of x[src], agg[n][128:192] = sum of edge_features.
// Unrolled x4 with dual accumulators: 8 loads (3 KB) in flight per wave
// instead of 2 — the R1 version was vmcnt-serialized (1.6 TB/s, VALU 10%).
__global__ __launch_bounds__(256) void k_gather(
        const float2* __restrict__ x2, const float* __restrict__ ef,
        const int* __restrict__ offsets, const int2* __restrict__ csr,
        float* __restrict__ agg, int N) {
    int wid = threadIdx.x >> 6;
    int lane = threadIdx.x & 63;
    int node = blockIdx.x * 4 + wid;
    if (node >= N) return;
    int start = offsets[node];
    int end = offsets[node + 1];
    float a0 = 0.f, a1 = 0.f, a2 = 0.f;
    float b0 = 0.f, b1 = 0.f, b2 = 0.f;
    for (int base = start; base < end; base += 64) {
        int m = end - base;
        if (m > 64) m = 64;
        int2 ent = make_int2(0, 0);
        if (lane < m) ent = csr[base + lane];
        int j = 0;
        for (; j + 4 <= m; j += 4) {
            int s0 = __shfl(ent.x, j,     64), id0 = __shfl(ent.y, j,     64);
            int s1 = __shfl(ent.x, j + 1, 64), id1 = __shfl(ent.y, j + 1, 64);
            int s2 = __shfl(ent.x, j + 2, 64), id2 = __shfl(ent.y, j + 2, 64);
            int s3 = __shfl(ent.x, j + 3, 64), id3 = __shfl(ent.y, j + 3, 64);
            float2 xa = x2[(size_t)s0 * 64 + lane];
            float2 xb = x2[(size_t)s1 * 64 + lane];
            float2 xc = x2[(size_t)s2 * 64 + lane];
            float2 xd = x2[(size_t)s3 * 64 + lane];
            float  e0 = ef[(size_t)id0 * 64 + lane];
            float  e1 = ef[(size_t)id1 * 64 + lane];
            float  e2 = ef[(size_t)id2 * 64 + lane];
            float  e3 = ef[(size_t)id3 * 64 + lane];
            a0 += xa.x; a1 += xa.y; a2 += e0;
            b0 += xb.x; b1 += xb.y; b2 += e1;
            a0 += xc.x; a1 += xc.y; a2 += e2;
            b0 += xd.x; b1 += xd.y; b2 += e3;
        }
        for (; j < m; ++j) {
            int s  = __shfl(ent.x, j, 64);
            int id = __shfl(ent.y, j, 64);
            float2 xv = x2[(size_t)s * 64 + lane];
            float  ev = ef[(size_t)id * 64 + lane];
            a0 += xv.x; a1 += xv.y; a2 += ev;
        }
    }
    a0 += b0; a1 += b1; a2 += b2;
    float2* aggrow = (float2*)(agg + (size_t)node * D_IN);
    aggrow[lane] = make_float2(a0, a1);              // x part, elems 2*lane..2*lane+1
    agg[(size_t)node * D_IN + 128 + lane] = a2;      // ef part
}

// ---------------- small GEMM: out[n,o] = agg[n,:]@W[:,o]/cnt + b[o] ----------------
__global__ __launch_bounds__(256) void k_gemm(
        const float* __restrict__ agg, const float* __restrict__ W,
        const float* __restrict__ b, const int* __restrict__ offsets,
        float* __restrict__ out, int N) {
    __shared__ float sAgg[16][D_IN];
    __shared__ int scnt[16];
    int tid = threadIdx.x;
    int n0 = blockIdx.x * 16;
    for (int i = tid; i < 16 * D_IN; i += 256) {
        int m = i / D_IN;
        int k = i - m * D_IN;
        int n = n0 + m;
        sAgg[m][k] = (n < N) ? agg[(size_t)n * D_IN + k] : 0.0f;
    }
    if (tid < 16) {
        int n = n0 + tid;
        scnt[tid] = (n < N) ? (offsets[n + 1] - offsets[n]) : 0;
    }
    __syncthreads();
    int o = tid & 127;
    int g = tid >> 7;   // 0..1: which group of 8 nodes
    float acc[8];
#pragma unroll
    for (int m = 0; m < 8; ++m) acc[m] = 0.0f;
    for (int k = 0; k < D_IN; k += 4) {
        float w0 = W[(k + 0) * D_OUT + o];
        float w1 = W[(k + 1) * D_OUT + o];
        float w2 = W[(k + 2) * D_OUT + o];
        float w3 = W[(k + 3) * D_OUT + o];
#pragma unroll
        for (int m = 0; m < 8; ++m) {
            const float4 av = *(const float4*)(&sAgg[g * 8 + m][k]);
            acc[m] += av.x * w0 + av.y * w1 + av.z * w2 + av.w * w3;
        }
    }
    float bo = b[o];
#pragma unroll
    for (int m = 0; m < 8; ++m) {
        int n = n0 + g * 8 + m;
        if (n < N) {
            int c = scnt[g * 8 + m];
            out[(size_t)n * D_OUT + o] = (c > 0) ? (acc[m] / (float)c + bo) : 0.0f;
        }
    }
}

extern "C" void kernel_launch(void* const* d_in, const int* in_sizes, int n_in,
                              void* d_out, int out_size, void* d_ws, size_t ws_size,
                              hipStream_t stream) {
    const float* x  = (const float*)d_in[0];
    const int*   ei = (const int*)d_in[1];   // [2, E] flat: src at [0,E), dst at [E,2E)
    const float* ef = (const float*)d_in[2];
    const float* W  = (const float*)d_in[3];
    const float* b  = (const float*)d_in[4];
    float* out = (float*)d_out;

    const int N = in_sizes[0] / D_NODE;
    const int E = in_sizes[2] / D_EDGE;

    // workspace layout (64B aligned)
    auto align64 = [](size_t v) { return (v + 63) & ~(size_t)63; };
    char* ws = (char*)d_ws;
    size_t o_cnt = 0;
    size_t o_off = align64(o_cnt + (size_t)N * 4);
    size_t o_cur = align64(o_off + (size_t)(N + 1) * 4);
    size_t o_csr = align64(o_cur + (size_t)N * 4);
    size_t o_agg = align64(o_csr + (size_t)E * 8);
    int*  cnt     = (int*)(ws + o_cnt);
    int*  offsets = (int*)(ws + o_off);
    int*  cursor  = (int*)(ws + o_cur);
    int2* csr     = (int2*)(ws + o_csr);
    float* agg    = (float*)(ws + o_agg);

    hipMemsetAsync(cnt, 0, (size_t)N * 4, stream);
    k_hist<<<(E + 255) / 256, 256, 0, stream>>>(ei + E, cnt, E);
    k_scan<<<1, 1024, 0, stream>>>(cnt, offsets, cursor, N);
    k_scatter<<<(E + 255) / 256, 256, 0, stream>>>(ei, cursor, csr, E);
    k_gather<<<(N + 3) / 4, 256, 0, stream>>>((const float2*)x, ef, offsets, csr, agg, N);
    k_gemm<<<(N + 15) / 16, 256, 0, stream>>>(agg, W, b, offsets, out, N);
}